// Round 1
// baseline (226.538 us; speedup 1.0000x reference)
//
#include <hip/hip_runtime.h>

#define B_    64
#define N_    512
#define DIN_  256
#define DOUT_ 256
#define EPS_  1e-5f

constexpr int BM = 64, BN = 64, BK = 32;

// C[M,Nc] = A[M,K] @ B[K,Nc] (+bias), row-major, optional batch via blockIdx.z strides.
template <bool ADD_BIAS>
__global__ __launch_bounds__(256) void gemm_tiled(
    const float* __restrict__ Aall, const float* __restrict__ Ball,
    const float* __restrict__ bias, float* __restrict__ Call,
    int M, int K, int Nc, long sA, long sB, long sC)
{
    const float* A  = Aall + (size_t)blockIdx.z * sA;
    const float* Bm = Ball + (size_t)blockIdx.z * sB;
    float*       C  = Call + (size_t)blockIdx.z * sC;

    __shared__ float As[BM][BK + 4];   // +4 pad: breaks 4-way bank conflict on row reads, keeps 16B align
    __shared__ float Bs[BK][BN];

    const int tid = threadIdx.x;
    const int tx = tid & 15, ty = tid >> 4;
    const int rowBase = blockIdx.x * BM;
    const int colBase = blockIdx.y * BN;

    float acc[4][4] = {};

    for (int k0 = 0; k0 < K; k0 += BK) {
        // stage A tile (64x32): 2 float4 per thread, coalesced along k
        #pragma unroll
        for (int i = 0; i < 2; ++i) {
            int idx = tid + i * 256;
            int r = idx >> 3, kq = idx & 7;
            float4 v = *reinterpret_cast<const float4*>(
                &A[(size_t)(rowBase + r) * K + k0 + kq * 4]);
            *reinterpret_cast<float4*>(&As[r][kq * 4]) = v;
        }
        // stage B tile (32x64): 2 float4 per thread, coalesced along cols
        #pragma unroll
        for (int i = 0; i < 2; ++i) {
            int idx = tid + i * 256;
            int r = idx >> 4, cq = idx & 15;
            *reinterpret_cast<float4*>(&Bs[r][cq * 4]) =
                *reinterpret_cast<const float4*>(
                    &Bm[(size_t)(k0 + r) * Nc + colBase + cq * 4]);
        }
        __syncthreads();

        #pragma unroll
        for (int k4 = 0; k4 < BK / 4; ++k4) {
            float4 a[4];
            #pragma unroll
            for (int i = 0; i < 4; ++i)
                a[i] = *reinterpret_cast<const float4*>(&As[ty * 4 + i][k4 * 4]);
            #pragma unroll
            for (int kk = 0; kk < 4; ++kk) {
                float4 b = *reinterpret_cast<const float4*>(&Bs[k4 * 4 + kk][tx * 4]);
                #pragma unroll
                for (int i = 0; i < 4; ++i) {
                    float av = (&a[i].x)[kk];
                    acc[i][0] = fmaf(av, b.x, acc[i][0]);
                    acc[i][1] = fmaf(av, b.y, acc[i][1]);
                    acc[i][2] = fmaf(av, b.z, acc[i][2]);
                    acc[i][3] = fmaf(av, b.w, acc[i][3]);
                }
            }
        }
        __syncthreads();
    }

    #pragma unroll
    for (int i = 0; i < 4; ++i) {
        float4 v = make_float4(acc[i][0], acc[i][1], acc[i][2], acc[i][3]);
        if (ADD_BIAS) {
            const float4 bv = *reinterpret_cast<const float4*>(&bias[colBase + tx * 4]);
            v.x += bv.x; v.y += bv.y; v.z += bv.z; v.w += bv.w;
        }
        *reinterpret_cast<float4*>(
            &C[(size_t)(rowBase + ty * 4 + i) * Nc + colBase + tx * 4]) = v;
    }
}

// Per-channel masked sum / sumsq / count over all B*N rows. stats must be pre-zeroed.
// stats[0..255]=sum, [256..511]=sumsq, [512]=count
__global__ __launch_bounds__(256) void reduce_stats(
    const float* __restrict__ y2, const float* __restrict__ mask,
    float* __restrict__ stats)
{
    const int e = threadIdx.x;
    const int rows = B_ * N_;
    const int chunk = rows / gridDim.x;
    const int r0 = blockIdx.x * chunk;
    float s = 0.f, ss = 0.f, cnt = 0.f;
    for (int r = r0; r < r0 + chunk; ++r) {
        float m = mask[r];
        float v = y2[(size_t)r * DOUT_ + e];
        float vm = v * m;
        s += vm;
        ss = fmaf(v, vm, ss);
        cnt += m;
    }
    atomicAdd(&stats[e], s);
    atomicAdd(&stats[DOUT_ + e], ss);
    if (e == 0) atomicAdd(&stats[2 * DOUT_], cnt);
}

// scale[e] = rsqrt(var+eps)*gamma[e]; shift[e] = beta[e] - mean*scale[e]
__global__ void finalize_stats(const float* __restrict__ stats,
                               const float* __restrict__ gamma,
                               const float* __restrict__ beta,
                               float* __restrict__ scsh)
{
    int e = threadIdx.x;
    float n = stats[2 * DOUT_];
    float mean = stats[e] / n;
    float var = stats[DOUT_ + e] / n - mean * mean;
    float sc = rsqrtf(var + EPS_) * gamma[e];
    scsh[e] = sc;
    scsh[DOUT_ + e] = beta[e] - mean * sc;
}

// y2 = relu((y2*scale + shift) * mask), in place. thread = channel, loop rows.
__global__ __launch_bounds__(256) void norm_relu(
    float* __restrict__ y2, const float* __restrict__ mask,
    const float* __restrict__ scsh)
{
    const int e = threadIdx.x;
    const float sc = scsh[e];
    const float sh = scsh[DOUT_ + e];
    const int rows = B_ * N_;
    const int chunk = rows / gridDim.x;
    const int r0 = blockIdx.x * chunk;
    for (int r = r0; r < r0 + chunk; ++r) {
        float m = mask[r];
        size_t off = (size_t)r * DOUT_ + e;
        float z = fmaf(y2[off], sc, sh) * m;
        y2[off] = fmaxf(z, 0.f);
    }
}

extern "C" void kernel_launch(void* const* d_in, const int* in_sizes, int n_in,
                              void* d_out, int out_size, void* d_ws, size_t ws_size,
                              hipStream_t stream)
{
    const float* x      = (const float*)d_in[0];
    const float* adj    = (const float*)d_in[1];
    const float* mask   = (const float*)d_in[2];
    const float* weight = (const float*)d_in[3];
    const float* bias   = (const float*)d_in[4];
    const float* gamma  = (const float*)d_in[5];
    const float* beta   = (const float*)d_in[6];
    float* out = (float*)d_out;

    float* y1    = (float*)d_ws;                          // B*N*DIN f32 = 33.5 MB
    float* stats = y1 + (size_t)B_ * N_ * DIN_;           // 2*DOUT+1
    float* scsh  = stats + 2 * DOUT_ + 1;                 // 2*DOUT

    hipMemsetAsync(stats, 0, (2 * DOUT_ + 1) * sizeof(float), stream);

    // y1[b] = adj[b] @ x[b]   (M=512, K=512, Nc=256, batched over 64)
    dim3 g1(N_ / BM, DIN_ / BN, B_);
    gemm_tiled<false><<<g1, 256, 0, stream>>>(
        adj, x, nullptr, y1,
        N_, N_, DIN_, (long)N_ * N_, (long)N_ * DIN_, (long)N_ * DIN_);

    // out = y1 @ W + bias     (flat M = B*N = 32768, K=256, Nc=256)
    dim3 g2((B_ * N_) / BM, DOUT_ / BN, 1);
    gemm_tiled<true><<<g2, 256, 0, stream>>>(
        y1, weight, bias, out,
        B_ * N_, DIN_, DOUT_, 0, 0, 0);

    reduce_stats<<<1024, 256, 0, stream>>>(out, mask, stats);
    finalize_stats<<<1, 256, 0, stream>>>(stats, gamma, beta, scsh);
    norm_relu<<<1024, 256, 0, stream>>>(out, mask, scsh);
}

// Round 2
// 97.251 us; speedup vs baseline: 2.3294x; 2.3294x over previous
//
#include <hip/hip_runtime.h>

#define B_    64
#define N_    512
#define DIN_  256
#define DOUT_ 256
#define EPS_  1e-5f
#define ROWS_ (B_ * N_)   // 32768

typedef __attribute__((ext_vector_type(8))) short bf16x8;   // 8 bf16 in 4 VGPRs
typedef __attribute__((ext_vector_type(4))) float f32x4;
typedef __attribute__((ext_vector_type(4))) short short4v;

__device__ __forceinline__ short f2bf(float f) {
    unsigned u = __builtin_bit_cast(unsigned, f);
    u += 0x7fff + ((u >> 16) & 1);     // round-to-nearest-even
    return (short)(u >> 16);
}

// WT[e][k] = bf16(W[k][e]) — 256x256, done once per launch (reads L2-resident W)
__global__ __launch_bounds__(256) void wt_cvt(const float* __restrict__ W,
                                              short* __restrict__ WT) {
    int e = blockIdx.x, k = threadIdx.x;
    WT[e * 256 + k] = f2bf(W[k * 256 + e]);
}

// xw^T[e][n] = (x @ W)[n][e] in bf16.  C = X[32768x256] @ W[256x256].
// LDS tiles stored [rows][K] with 16B-slot XOR swizzle (slot ^= row&7).
__global__ __launch_bounds__(256) void gemm_xw(const float* __restrict__ X,
                                               const short* __restrict__ WT,
                                               short* __restrict__ xwT) {
    __shared__ short As[64 * 64];   // X tile   [n-row][k]
    __shared__ short Bs[64 * 64];   // W^T tile [e-col][k]
    const int tid = threadIdx.x;
    const int wv = tid >> 6, lane = tid & 63;
    const int lrow = lane & 15, lg = lane >> 4;
    const int wr = (wv >> 1) * 32, wc = (wv & 1) * 32;
    const int rowBase = blockIdx.x * 64;   // n
    const int colBase = blockIdx.y * 64;   // e

    const int sr = tid >> 2, sc = (tid & 3) * 16;   // staging: row, k-start
    f32x4 acc[2][2] = {};

    for (int k0 = 0; k0 < DIN_; k0 += 64) {
        {   // stage A: 16 f32 -> 16 bf16 per thread
            const float* src = &X[(size_t)(rowBase + sr) * DIN_ + k0 + sc];
            float4 v0 = *(const float4*)(src);
            float4 v1 = *(const float4*)(src + 4);
            float4 v2 = *(const float4*)(src + 8);
            float4 v3 = *(const float4*)(src + 12);
            bf16x8 h0 = { f2bf(v0.x), f2bf(v0.y), f2bf(v0.z), f2bf(v0.w),
                          f2bf(v1.x), f2bf(v1.y), f2bf(v1.z), f2bf(v1.w) };
            bf16x8 h1 = { f2bf(v2.x), f2bf(v2.y), f2bf(v2.z), f2bf(v2.w),
                          f2bf(v3.x), f2bf(v3.y), f2bf(v3.z), f2bf(v3.w) };
            int s0 = sc >> 3;
            *(bf16x8*)&As[sr * 64 + (((s0    ) ^ (sr & 7)) << 3)] = h0;
            *(bf16x8*)&As[sr * 64 + (((s0 + 1) ^ (sr & 7)) << 3)] = h1;
        }
        {   // stage B: WT already bf16, 16 shorts per thread
            const short* src = &WT[(size_t)(colBase + sr) * DIN_ + k0 + sc];
            bf16x8 b0 = *(const bf16x8*)(src);
            bf16x8 b1 = *(const bf16x8*)(src + 8);
            int s0 = sc >> 3;
            *(bf16x8*)&Bs[sr * 64 + (((s0    ) ^ (sr & 7)) << 3)] = b0;
            *(bf16x8*)&Bs[sr * 64 + (((s0 + 1) ^ (sr & 7)) << 3)] = b1;
        }
        __syncthreads();
        #pragma unroll
        for (int s = 0; s < 2; ++s) {
            bf16x8 a[2], b[2];
            #pragma unroll
            for (int m = 0; m < 2; ++m) {
                int r = wr + m * 16 + lrow;
                a[m] = *(const bf16x8*)&As[r * 64 + (((s * 4 + lg) ^ (r & 7)) << 3)];
            }
            #pragma unroll
            for (int n = 0; n < 2; ++n) {
                int c = wc + n * 16 + lrow;
                b[n] = *(const bf16x8*)&Bs[c * 64 + (((s * 4 + lg) ^ (c & 7)) << 3)];
            }
            #pragma unroll
            for (int m = 0; m < 2; ++m)
                #pragma unroll
                for (int n = 0; n < 2; ++n)
                    acc[m][n] = __builtin_amdgcn_mfma_f32_16x16x32_bf16(a[m], b[n], acc[m][n], 0, 0, 0);
        }
        __syncthreads();
    }
    // epilogue: write transposed (xwT[e][n]); 4 regs = 4 consecutive n -> 8B store
    #pragma unroll
    for (int m = 0; m < 2; ++m)
        #pragma unroll
        for (int n = 0; n < 2; ++n) {
            int e  = colBase + wc + n * 16 + lrow;
            int nr = rowBase + wr + m * 16 + lg * 4;
            short4v o = { f2bf(acc[m][n][0]), f2bf(acc[m][n][1]),
                          f2bf(acc[m][n][2]), f2bf(acc[m][n][3]) };
            *(short4v*)&xwT[(size_t)e * ROWS_ + nr] = o;
        }
}

// y2[b] = adj[b] @ xw[b] + bias.  Per-batch M=512, K=512, N=256 (full width).
// 512 threads (8 waves, 2Mx4N), tile 64x256, BK=64.
__global__ __launch_bounds__(512) void gemm_y2(const float* __restrict__ adj,
                                               const short* __restrict__ xwT,
                                               const float* __restrict__ bias,
                                               float* __restrict__ y2) {
    __shared__ short As[64 * 64];    // adj tile [row][k]   8 KB
    __shared__ short Bs[256 * 64];   // xw^T tile [col][k] 32 KB
    const int tid = threadIdx.x;
    const int wv = tid >> 6, lane = tid & 63;
    const int lrow = lane & 15, lg = lane >> 4;
    const int wr = (wv >> 2) * 32, wc = (wv & 3) * 64;
    const int bz = blockIdx.z;
    const int rowBase = blockIdx.x * 64;

    const float* A = adj + (size_t)bz * N_ * N_;
    f32x4 acc[2][4] = {};

    const int ar = tid >> 3, ac = (tid & 7) * 8;    // A staging: 8 f32/thread
    const int bc = tid >> 1, bk = (tid & 1) * 32;   // B staging: 32 shorts/thread

    for (int k0 = 0; k0 < N_; k0 += 64) {
        {   // stage adj tile, f32 -> bf16
            const float* src = &A[(size_t)(rowBase + ar) * N_ + k0 + ac];
            float4 v0 = *(const float4*)(src);
            float4 v1 = *(const float4*)(src + 4);
            bf16x8 h = { f2bf(v0.x), f2bf(v0.y), f2bf(v0.z), f2bf(v0.w),
                         f2bf(v1.x), f2bf(v1.y), f2bf(v1.z), f2bf(v1.w) };
            int slot = ac >> 3;
            *(bf16x8*)&As[ar * 64 + ((slot ^ (ar & 7)) << 3)] = h;
        }
        {   // stage xw^T tile (already bf16, contiguous in k)
            const short* src = &xwT[(size_t)bc * ROWS_ + bz * N_ + k0 + bk];
            #pragma unroll
            for (int j = 0; j < 4; ++j) {
                bf16x8 v = *(const bf16x8*)(src + j * 8);
                int slot = (bk >> 3) + j;
                *(bf16x8*)&Bs[bc * 64 + ((slot ^ (bc & 7)) << 3)] = v;
            }
        }
        __syncthreads();
        #pragma unroll
        for (int s = 0; s < 2; ++s) {
            bf16x8 a[2], b[4];
            #pragma unroll
            for (int m = 0; m < 2; ++m) {
                int r = wr + m * 16 + lrow;
                a[m] = *(const bf16x8*)&As[r * 64 + (((s * 4 + lg) ^ (r & 7)) << 3)];
            }
            #pragma unroll
            for (int n = 0; n < 4; ++n) {
                int c = wc + n * 16 + lrow;
                b[n] = *(const bf16x8*)&Bs[c * 64 + (((s * 4 + lg) ^ (c & 7)) << 3)];
            }
            #pragma unroll
            for (int m = 0; m < 2; ++m)
                #pragma unroll
                for (int n = 0; n < 4; ++n)
                    acc[m][n] = __builtin_amdgcn_mfma_f32_16x16x32_bf16(a[m], b[n], acc[m][n], 0, 0, 0);
        }
        __syncthreads();
    }
    float* C = y2 + (size_t)bz * N_ * DOUT_;
    #pragma unroll
    for (int m = 0; m < 2; ++m)
        #pragma unroll
        for (int n = 0; n < 4; ++n) {
            int col = wc + n * 16 + lrow;
            float bv = bias[col];
            int r0 = rowBase + wr + m * 16 + lg * 4;
            #pragma unroll
            for (int r = 0; r < 4; ++r)
                C[(size_t)(r0 + r) * DOUT_ + col] = acc[m][n][r] + bv;
        }
}

// Deterministic two-stage masked stats: per-block partials (no atomics).
__global__ __launch_bounds__(256) void reduce_stats(const float* __restrict__ y2,
                                                    const float* __restrict__ mask,
                                                    float* __restrict__ psum,
                                                    float* __restrict__ psumsq,
                                                    float* __restrict__ pcnt) {
    const int e = threadIdx.x;
    const int r0 = blockIdx.x * 128;
    float s = 0.f, ss = 0.f, cnt = 0.f;
    for (int r = r0; r < r0 + 128; ++r) {
        float m = mask[r];
        float v = y2[(size_t)r * DOUT_ + e];
        s += v * m;
        ss = fmaf(v, v * m, ss);
        cnt += m;
    }
    psum[blockIdx.x * DOUT_ + e] = s;
    psumsq[blockIdx.x * DOUT_ + e] = ss;
    if (e == 0) pcnt[blockIdx.x] = cnt;
}

__global__ void finalize_stats(const float* __restrict__ psum,
                               const float* __restrict__ psumsq,
                               const float* __restrict__ pcnt,
                               const float* __restrict__ gamma,
                               const float* __restrict__ beta,
                               float* __restrict__ scsh) {
    int e = threadIdx.x;
    float s = 0.f, ss = 0.f, n = 0.f;
    for (int j = 0; j < 256; ++j) {
        s += psum[j * DOUT_ + e];
        ss += psumsq[j * DOUT_ + e];
        n += pcnt[j];
    }
    float mean = s / n;
    float var = ss / n - mean * mean;
    float sc = rsqrtf(var + EPS_) * gamma[e];
    scsh[e] = sc;
    scsh[DOUT_ + e] = beta[e] - mean * sc;
}

// y2 = relu((y2*scale + shift) * mask), float4-vectorized, in place.
__global__ __launch_bounds__(256) void norm_relu(float* __restrict__ y2,
                                                 const float* __restrict__ mask,
                                                 const float* __restrict__ scsh) {
    const int nq = ROWS_ * (DOUT_ / 4);
    for (int q = blockIdx.x * blockDim.x + threadIdx.x; q < nq;
         q += gridDim.x * blockDim.x) {
        int e4 = (q & 63) * 4;
        int r = q >> 6;
        float m = mask[r];
        float4 v  = *(float4*)&y2[(size_t)q * 4];
        float4 sc = *(const float4*)&scsh[e4];
        float4 sh = *(const float4*)&scsh[DOUT_ + e4];
        v.x = fmaxf(fmaf(v.x, sc.x, sh.x) * m, 0.f);
        v.y = fmaxf(fmaf(v.y, sc.y, sh.y) * m, 0.f);
        v.z = fmaxf(fmaf(v.z, sc.z, sh.z) * m, 0.f);
        v.w = fmaxf(fmaf(v.w, sc.w, sh.w) * m, 0.f);
        *(float4*)&y2[(size_t)q * 4] = v;
    }
}

extern "C" void kernel_launch(void* const* d_in, const int* in_sizes, int n_in,
                              void* d_out, int out_size, void* d_ws, size_t ws_size,
                              hipStream_t stream) {
    const float* x      = (const float*)d_in[0];
    const float* adj    = (const float*)d_in[1];
    const float* mask   = (const float*)d_in[2];
    const float* weight = (const float*)d_in[3];
    const float* bias   = (const float*)d_in[4];
    const float* gamma  = (const float*)d_in[5];
    const float* beta   = (const float*)d_in[6];
    float* out = (float*)d_out;

    short* WT     = (short*)d_ws;                          // 128 KB
    short* xwT    = WT + 256 * 256;                        // 16.8 MB
    float* psum   = (float*)(xwT + (size_t)DOUT_ * ROWS_); // 256 KB
    float* psumsq = psum + 256 * DOUT_;                    // 256 KB
    float* pcnt   = psumsq + 256 * DOUT_;                  // 1 KB
    float* scsh   = pcnt + 256;                            // 2 KB

    wt_cvt<<<256, 256, 0, stream>>>(weight, WT);
    gemm_xw<<<dim3(ROWS_ / 64, DOUT_ / 64), 256, 0, stream>>>(x, WT, xwT);
    gemm_y2<<<dim3(N_ / 64, 1, B_), 512, 0, stream>>>(adj, xwT, bias, out);
    reduce_stats<<<256, 256, 0, stream>>>(out, mask, psum, psumsq, pcnt);
    finalize_stats<<<1, 256, 0, stream>>>(psum, psumsq, pcnt, gamma, beta, scsh);
    norm_relu<<<2048, 256, 0, stream>>>(out, mask, scsh);
}

// Round 3
// 82.054 us; speedup vs baseline: 2.7608x; 1.1852x over previous
//
#include <hip/hip_runtime.h>

#define B_    64
#define N_    512
#define DIN_  256
#define DOUT_ 256
#define EPS_  1e-5f
#define ROWS_ (B_ * N_)   // 32768
#define NBLK_Y2 512

typedef __attribute__((ext_vector_type(8))) short bf16x8;   // 8 bf16 in 4 VGPRs
typedef __attribute__((ext_vector_type(4))) float f32x4;
typedef __attribute__((ext_vector_type(4))) short short4v;

__device__ __forceinline__ short f2bf(float f) {
    unsigned u = __builtin_bit_cast(unsigned, f);
    u += 0x7fff + ((u >> 16) & 1);     // round-to-nearest-even
    return (short)(u >> 16);
}

// async global->LDS, 16B per lane; LDS dest must be linear (base + lane*16)
__device__ __forceinline__ void gload_lds16(const void* g, void* l) {
    __builtin_amdgcn_global_load_lds(
        (const __attribute__((address_space(1))) void*)g,
        (__attribute__((address_space(3))) void*)l, 16, 0, 0);
}

// WT[e][k] = bf16(W[k][e])
__global__ __launch_bounds__(256) void wt_cvt(const float* __restrict__ W,
                                              short* __restrict__ WT) {
    int e = blockIdx.x, k = threadIdx.x;
    WT[e * 256 + k] = f2bf(W[k * 256 + e]);
}

// xw^T[e][n] = (x @ W)[n][e] bf16.  Double-buffered 2-phase pipeline.
__global__ __launch_bounds__(256, 4) void gemm_xw(const float* __restrict__ X,
                                                  const short* __restrict__ WT,
                                                  short* __restrict__ xwT) {
    __shared__ short As[2][64 * 64];   // X tile   [n-row][k], swizzled
    __shared__ short Bs[2][64 * 64];   // W^T tile [e-col][k], swizzled
    const int tid = threadIdx.x;
    const int wv = tid >> 6, lane = tid & 63;
    const int lrow = lane & 15, lg = lane >> 4;
    const int wr = (wv >> 1) * 32, wc = (wv & 1) * 32;

    // XCD-chunked swizzle: 2048 blocks, 256 contiguous work-items per XCD
    const int swz = ((blockIdx.x & 7) << 8) + (blockIdx.x >> 3);
    const int rowBase = (swz >> 2) * 64;
    const int colBase = (swz & 3) * 64;

    const int sr = tid >> 2, sc = (tid & 3) * 16;   // A staging: 16 f32/thread
    const int s0 = sc >> 3;
    f32x4 acc[2][2] = {};

    // ---- prologue: stage tile 0 ----
    #pragma unroll
    for (int j = 0; j < 2; ++j) {
        int o = (wv << 11) + (j << 10) + (lane << 4);
        int c = o >> 7, p = (o >> 4) & 7;
        gload_lds16(&WT[(size_t)(colBase + c) * DIN_ + ((p ^ (c & 7)) << 3)],
                    (char*)&Bs[0][0] + o);
    }
    {
        const float* src = &X[(size_t)(rowBase + sr) * DIN_ + sc];
        float4 v0 = *(const float4*)(src);
        float4 v1 = *(const float4*)(src + 4);
        float4 v2 = *(const float4*)(src + 8);
        float4 v3 = *(const float4*)(src + 12);
        bf16x8 h0 = { f2bf(v0.x), f2bf(v0.y), f2bf(v0.z), f2bf(v0.w),
                      f2bf(v1.x), f2bf(v1.y), f2bf(v1.z), f2bf(v1.w) };
        bf16x8 h1 = { f2bf(v2.x), f2bf(v2.y), f2bf(v2.z), f2bf(v2.w),
                      f2bf(v3.x), f2bf(v3.y), f2bf(v3.z), f2bf(v3.w) };
        *(bf16x8*)&As[0][sr * 64 + (((s0    ) ^ (sr & 7)) << 3)] = h0;
        *(bf16x8*)&As[0][sr * 64 + (((s0 + 1) ^ (sr & 7)) << 3)] = h1;
    }
    __syncthreads();

    int cur = 0;
    for (int t = 0; t < 4; ++t) {
        float4 v0, v1, v2, v3;
        if (t < 3) {   // issue next-tile loads BEFORE compute (overlap with MFMA)
            const int k0 = (t + 1) * 64;
            #pragma unroll
            for (int j = 0; j < 2; ++j) {
                int o = (wv << 11) + (j << 10) + (lane << 4);
                int c = o >> 7, p = (o >> 4) & 7;
                gload_lds16(&WT[(size_t)(colBase + c) * DIN_ + k0 + ((p ^ (c & 7)) << 3)],
                            (char*)&Bs[cur ^ 1][0] + o);
            }
            const float* src = &X[(size_t)(rowBase + sr) * DIN_ + k0 + sc];
            v0 = *(const float4*)(src);
            v1 = *(const float4*)(src + 4);
            v2 = *(const float4*)(src + 8);
            v3 = *(const float4*)(src + 12);
        }
        #pragma unroll
        for (int s = 0; s < 2; ++s) {
            bf16x8 a[2], b[2];
            #pragma unroll
            for (int m = 0; m < 2; ++m) {
                int r = wr + m * 16 + lrow;
                a[m] = *(const bf16x8*)&As[cur][r * 64 + (((s * 4 + lg) ^ (r & 7)) << 3)];
            }
            #pragma unroll
            for (int n = 0; n < 2; ++n) {
                int c = wc + n * 16 + lrow;
                b[n] = *(const bf16x8*)&Bs[cur][c * 64 + (((s * 4 + lg) ^ (c & 7)) << 3)];
            }
            #pragma unroll
            for (int m = 0; m < 2; ++m)
                #pragma unroll
                for (int n = 0; n < 2; ++n)
                    acc[m][n] = __builtin_amdgcn_mfma_f32_16x16x32_bf16(a[m], b[n], acc[m][n], 0, 0, 0);
        }
        if (t < 3) {   // write-late: A cvt + ds_write after compute
            bf16x8 h0 = { f2bf(v0.x), f2bf(v0.y), f2bf(v0.z), f2bf(v0.w),
                          f2bf(v1.x), f2bf(v1.y), f2bf(v1.z), f2bf(v1.w) };
            bf16x8 h1 = { f2bf(v2.x), f2bf(v2.y), f2bf(v2.z), f2bf(v2.w),
                          f2bf(v3.x), f2bf(v3.y), f2bf(v3.z), f2bf(v3.w) };
            *(bf16x8*)&As[cur ^ 1][sr * 64 + (((s0    ) ^ (sr & 7)) << 3)] = h0;
            *(bf16x8*)&As[cur ^ 1][sr * 64 + (((s0 + 1) ^ (sr & 7)) << 3)] = h1;
        }
        __syncthreads();   // single barrier per K-step (drains vmcnt+lgkmcnt)
        cur ^= 1;
    }
    // epilogue: write transposed bf16
    #pragma unroll
    for (int m = 0; m < 2; ++m)
        #pragma unroll
        for (int n = 0; n < 2; ++n) {
            int e  = colBase + wc + n * 16 + lrow;
            int nr = rowBase + wr + m * 16 + lg * 4;
            short4v o = { f2bf(acc[m][n][0]), f2bf(acc[m][n][1]),
                          f2bf(acc[m][n][2]), f2bf(acc[m][n][3]) };
            *(short4v*)&xwT[(size_t)e * ROWS_ + nr] = o;
        }
}

// y2[b] = adj[b] @ xw[b] + bias, with fused masked per-channel partial stats.
__global__ __launch_bounds__(512, 4) void gemm_y2(const float* __restrict__ adj,
                                                  const short* __restrict__ xwT,
                                                  const float* __restrict__ bias,
                                                  const float* __restrict__ mask,
                                                  float* __restrict__ y2,
                                                  float* __restrict__ psum,
                                                  float* __restrict__ psumsq,
                                                  float* __restrict__ pcnt) {
    __shared__ short As[2][64 * 64];    // adj tile, 16 KB
    __shared__ short Bs[2][256 * 64];   // xw^T tile, 64 KB
    const int tid = threadIdx.x;
    const int wv = tid >> 6, lane = tid & 63;
    const int lrow = lane & 15, lg = lane >> 4;
    const int wr = (wv >> 2) * 32, wc = (wv & 3) * 64;

    // XCD-chunked swizzle: 512 blocks -> 64 contiguous work-items per XCD
    // => all 8 tiles of a batch land on one XCD (xwT slice L2-resident)
    const int swz = ((blockIdx.x & 7) << 6) + (blockIdx.x >> 3);
    const int bz = swz >> 3;
    const int rowBase = (swz & 7) * 64;

    const float* A = adj + (size_t)bz * N_ * N_;
    const int ar = tid >> 3, ac = (tid & 7) * 8;
    const int s0a = tid & 7;

    f32x4 acc[2][4] = {};

    // ---- prologue: stage tile 0 ----
    #pragma unroll
    for (int j = 0; j < 4; ++j) {
        int o = (wv << 12) + (j << 10) + (lane << 4);
        int c = o >> 7, p = (o >> 4) & 7;
        gload_lds16(&xwT[(size_t)c * ROWS_ + bz * N_ + ((p ^ (c & 7)) << 3)],
                    (char*)&Bs[0][0] + o);
    }
    {
        const float* src = &A[(size_t)(rowBase + ar) * N_ + ac];
        float4 v0 = *(const float4*)(src);
        float4 v1 = *(const float4*)(src + 4);
        bf16x8 h = { f2bf(v0.x), f2bf(v0.y), f2bf(v0.z), f2bf(v0.w),
                     f2bf(v1.x), f2bf(v1.y), f2bf(v1.z), f2bf(v1.w) };
        *(bf16x8*)&As[0][ar * 64 + ((s0a ^ (ar & 7)) << 3)] = h;
    }
    __syncthreads();

    int cur = 0;
    for (int t = 0; t < 8; ++t) {
        float4 v0, v1;
        if (t < 7) {   // issue next-tile loads before compute
            const int k0 = (t + 1) * 64;
            #pragma unroll
            for (int j = 0; j < 4; ++j) {
                int o = (wv << 12) + (j << 10) + (lane << 4);
                int c = o >> 7, p = (o >> 4) & 7;
                gload_lds16(&xwT[(size_t)c * ROWS_ + bz * N_ + k0 + ((p ^ (c & 7)) << 3)],
                            (char*)&Bs[cur ^ 1][0] + o);
            }
            const float* src = &A[(size_t)(rowBase + ar) * N_ + k0 + ac];
            v0 = *(const float4*)(src);
            v1 = *(const float4*)(src + 4);
        }
        #pragma unroll
        for (int s = 0; s < 2; ++s) {
            bf16x8 a[2], b[4];
            #pragma unroll
            for (int m = 0; m < 2; ++m) {
                int r = wr + m * 16 + lrow;
                a[m] = *(const bf16x8*)&As[cur][r * 64 + (((s * 4 + lg) ^ (r & 7)) << 3)];
            }
            #pragma unroll
            for (int n = 0; n < 4; ++n) {
                int c = wc + n * 16 + lrow;
                b[n] = *(const bf16x8*)&Bs[cur][c * 64 + (((s * 4 + lg) ^ (c & 7)) << 3)];
            }
            #pragma unroll
            for (int m = 0; m < 2; ++m)
                #pragma unroll
                for (int n = 0; n < 4; ++n)
                    acc[m][n] = __builtin_amdgcn_mfma_f32_16x16x32_bf16(a[m], b[n], acc[m][n], 0, 0, 0);
        }
        if (t < 7) {
            bf16x8 h = { f2bf(v0.x), f2bf(v0.y), f2bf(v0.z), f2bf(v0.w),
                         f2bf(v1.x), f2bf(v1.y), f2bf(v1.z), f2bf(v1.w) };
            *(bf16x8*)&As[cur ^ 1][ar * 64 + ((s0a ^ (ar & 7)) << 3)] = h;
        }
        __syncthreads();
        cur ^= 1;
    }

    // ---- epilogue: bias + store + fused masked per-channel stats ----
    float* C = y2 + (size_t)bz * N_ * DOUT_;
    float sv[4] = {0.f, 0.f, 0.f, 0.f};
    float sq[4] = {0.f, 0.f, 0.f, 0.f};
    float mv[2][4];
    #pragma unroll
    for (int m = 0; m < 2; ++m)
        #pragma unroll
        for (int r = 0; r < 4; ++r)
            mv[m][r] = mask[bz * N_ + rowBase + wr + m * 16 + lg * 4 + r];
    #pragma unroll
    for (int m = 0; m < 2; ++m)
        #pragma unroll
        for (int n = 0; n < 4; ++n) {
            const int col = wc + n * 16 + lrow;
            const float bv = bias[col];
            const int r0 = rowBase + wr + m * 16 + lg * 4;
            #pragma unroll
            for (int r = 0; r < 4; ++r) {
                float v = acc[m][n][r] + bv;
                C[(size_t)(r0 + r) * DOUT_ + col] = v;
                float vm = v * mv[m][r];
                sv[n] += vm;
                sq[n] = fmaf(v, vm, sq[n]);
            }
        }
    // reduce over the 4 lane-groups (lanes differing in bits 4,5 share a col)
    #pragma unroll
    for (int n = 0; n < 4; ++n) {
        sv[n] += __shfl_xor(sv[n], 16); sv[n] += __shfl_xor(sv[n], 32);
        sq[n] += __shfl_xor(sq[n], 16); sq[n] += __shfl_xor(sq[n], 32);
    }
    float* sred = (float*)&As[0][0];   // reuse LDS (K-loop done): [8][64] + [8][64]
    if (lg == 0) {
        #pragma unroll
        for (int n = 0; n < 4; ++n) {
            sred[wv * 64 + n * 16 + lrow] = sv[n];
            sred[512 + wv * 64 + n * 16 + lrow] = sq[n];
        }
    }
    if (wv == 0) {   // masked row count for this block's 64 rows
        float cnt = mask[bz * N_ + rowBase + lane];
        #pragma unroll
        for (int i = 1; i < 64; i <<= 1) cnt += __shfl_xor(cnt, i);
        if (lane == 0) pcnt[blockIdx.x] = cnt;
    }
    __syncthreads();
    if (tid < 256) {   // col = tid; contributing waves: g and g+4
        const int g = tid >> 6, lo = tid & 63;
        psum[(size_t)blockIdx.x * DOUT_ + tid] =
            sred[g * 64 + lo] + sred[(g + 4) * 64 + lo];
        psumsq[(size_t)blockIdx.x * DOUT_ + tid] =
            sred[512 + g * 64 + lo] + sred[512 + (g + 4) * 64 + lo];
    }
}

__global__ void finalize_stats(const float* __restrict__ psum,
                               const float* __restrict__ psumsq,
                               const float* __restrict__ pcnt,
                               const float* __restrict__ gamma,
                               const float* __restrict__ beta,
                               float* __restrict__ scsh) {
    int e = threadIdx.x;
    float s = 0.f, ss = 0.f, n = 0.f;
    for (int j = 0; j < NBLK_Y2; ++j) {
        s += psum[(size_t)j * DOUT_ + e];
        ss += psumsq[(size_t)j * DOUT_ + e];
        n += pcnt[j];
    }
    float mean = s / n;
    float var = ss / n - mean * mean;
    float sc = rsqrtf(var + EPS_) * gamma[e];
    scsh[e] = sc;
    scsh[DOUT_ + e] = beta[e] - mean * sc;
}

__global__ __launch_bounds__(256) void norm_relu(float* __restrict__ y2,
                                                 const float* __restrict__ mask,
                                                 const float* __restrict__ scsh) {
    const int nq = ROWS_ * (DOUT_ / 4);
    for (int q = blockIdx.x * blockDim.x + threadIdx.x; q < nq;
         q += gridDim.x * blockDim.x) {
        int e4 = (q & 63) * 4;
        int r = q >> 6;
        float m = mask[r];
        float4 v  = *(float4*)&y2[(size_t)q * 4];
        float4 sc = *(const float4*)&scsh[e4];
        float4 sh = *(const float4*)&scsh[DOUT_ + e4];
        v.x = fmaxf(fmaf(v.x, sc.x, sh.x) * m, 0.f);
        v.y = fmaxf(fmaf(v.y, sc.y, sh.y) * m, 0.f);
        v.z = fmaxf(fmaf(v.z, sc.z, sh.z) * m, 0.f);
        v.w = fmaxf(fmaf(v.w, sc.w, sh.w) * m, 0.f);
        *(float4*)&y2[(size_t)q * 4] = v;
    }
}

extern "C" void kernel_launch(void* const* d_in, const int* in_sizes, int n_in,
                              void* d_out, int out_size, void* d_ws, size_t ws_size,
                              hipStream_t stream) {
    const float* x      = (const float*)d_in[0];
    const float* adj    = (const float*)d_in[1];
    const float* mask   = (const float*)d_in[2];
    const float* weight = (const float*)d_in[3];
    const float* bias   = (const float*)d_in[4];
    const float* gamma  = (const float*)d_in[5];
    const float* beta   = (const float*)d_in[6];
    float* out = (float*)d_out;

    short* WT     = (short*)d_ws;                          // 128 KB
    short* xwT    = WT + 256 * 256;                        // 16.8 MB
    float* psum   = (float*)(xwT + (size_t)DOUT_ * ROWS_); // 512 KB
    float* psumsq = psum + NBLK_Y2 * DOUT_;                // 512 KB
    float* pcnt   = psumsq + NBLK_Y2 * DOUT_;              // 2 KB
    float* scsh   = pcnt + NBLK_Y2;                        // 2 KB

    wt_cvt<<<256, 256, 0, stream>>>(weight, WT);
    gemm_xw<<<2048, 256, 0, stream>>>(x, WT, xwT);
    gemm_y2<<<NBLK_Y2, 512, 0, stream>>>(adj, xwT, bias, mask, out, psum, psumsq, pcnt);
    finalize_stats<<<1, 256, 0, stream>>>(psum, psumsq, pcnt, gamma, beta, scsh);
    norm_relu<<<2048, 256, 0, stream>>>(out, mask, scsh);
}

// Round 4
// 72.911 us; speedup vs baseline: 3.1071x; 1.1254x over previous
//
#include <hip/hip_runtime.h>

#define B_    64
#define N_    512
#define DIN_  256
#define DOUT_ 256
#define EPS_  1e-5f
#define ROWS_ (B_ * N_)   // 32768
#define NBLK_Y2 512       // one partial-stat row per (batch, row-tile)

typedef __attribute__((ext_vector_type(8))) short bf16x8;   // 8 bf16 = 4 VGPRs
typedef __attribute__((ext_vector_type(4))) float f32x4;
typedef __attribute__((ext_vector_type(4))) short short4v;

__device__ __forceinline__ short f2bf(float f) {
    unsigned u = __builtin_bit_cast(unsigned, f);
    u += 0x7fff + ((u >> 16) & 1);     // round-to-nearest-even
    return (short)(u >> 16);
}

// WT[e][k] = bf16(W[k][e]) — LDS-transposed, coalesced read AND write.
__global__ __launch_bounds__(256) void wt_cvt(const float* __restrict__ W,
                                              short* __restrict__ WT) {
    __shared__ float t[64][65];
    const int kb = (blockIdx.x >> 2) * 64, eb = (blockIdx.x & 3) * 64;
    const int r = threadIdx.x >> 4, c = (threadIdx.x & 15) * 4;
    #pragma unroll
    for (int i = 0; i < 4; ++i) {
        float4 v = *(const float4*)&W[(size_t)(kb + r + i * 16) * DOUT_ + eb + c];
        t[r + i * 16][c]     = v.x;
        t[r + i * 16][c + 1] = v.y;
        t[r + i * 16][c + 2] = v.z;
        t[r + i * 16][c + 3] = v.w;
    }
    __syncthreads();
    #pragma unroll
    for (int i = 0; i < 4; ++i) {
        int e = r + i * 16;
        short4v o = { f2bf(t[c][e]), f2bf(t[c + 1][e]),
                      f2bf(t[c + 2][e]), f2bf(t[c + 3][e]) };
        *(short4v*)&WT[(size_t)(eb + e) * DIN_ + kb + c] = o;
    }
}

// xw^T[e][n] = (x @ W)[n][e].  W^T held in registers (64 VGPR/wave);
// x row-panel staged once in LDS; inner loop = pure ds_read + MFMA.
__global__ __launch_bounds__(512, 3) void gemm_xw(const float* __restrict__ X,
                                                  const short* __restrict__ WT,
                                                  short* __restrict__ xwT) {
    __shared__ short As[64 * 256];   // 32 KB, [row][k] with 16B-slot XOR swizzle
    const int tid = threadIdx.x, wv = tid >> 6, lane = tid & 63;
    const int lrow = lane & 15, lg = lane >> 4;
    const int rowBase = blockIdx.x * 64;

    // B-regs: cols wv*32 + nf*16 + lrow, full K=256 (8 chunks of 32)
    bf16x8 b[2][8];
    #pragma unroll
    for (int nf = 0; nf < 2; ++nf) {
        const short* bp = &WT[(size_t)(wv * 32 + nf * 16 + lrow) * DIN_ + lg * 8];
        #pragma unroll
        for (int kk = 0; kk < 8; ++kk)
            b[nf][kk] = *(const bf16x8*)(bp + kk * 32);
    }
    // stage As once: 64 rows x 256 k, f32 -> bf16
    const int sr = tid >> 3, sk = (tid & 7) * 32;
    {
        const float* src = &X[(size_t)(rowBase + sr) * DIN_ + sk];
        short* dst = &As[sr * 256];
        #pragma unroll
        for (int j = 0; j < 4; ++j) {
            float4 v0 = *(const float4*)(src + j * 8);
            float4 v1 = *(const float4*)(src + j * 8 + 4);
            bf16x8 h = { f2bf(v0.x), f2bf(v0.y), f2bf(v0.z), f2bf(v0.w),
                         f2bf(v1.x), f2bf(v1.y), f2bf(v1.z), f2bf(v1.w) };
            int slot = (sk >> 3) + j;
            *(bf16x8*)(dst + (((slot ^ (sr & 7)) << 3))) = h;
        }
    }
    __syncthreads();

    f32x4 acc[4][2] = {};
    const int rb7 = lrow & 7;
    #pragma unroll
    for (int kk = 0; kk < 8; ++kk) {
        bf16x8 a[4];
        #pragma unroll
        for (int m = 0; m < 4; ++m)
            a[m] = *(const bf16x8*)&As[(m * 16 + lrow) * 256 +
                                       (((kk * 4 + lg) ^ rb7) << 3)];
        #pragma unroll
        for (int m = 0; m < 4; ++m)
            #pragma unroll
            for (int nf = 0; nf < 2; ++nf)
                acc[m][nf] = __builtin_amdgcn_mfma_f32_16x16x32_bf16(
                    a[m], b[nf][kk], acc[m][nf], 0, 0, 0);
    }
    // write transposed bf16
    #pragma unroll
    for (int m = 0; m < 4; ++m)
        #pragma unroll
        for (int nf = 0; nf < 2; ++nf) {
            int e  = wv * 32 + nf * 16 + lrow;
            int nr = rowBase + m * 16 + lg * 4;
            short4v o = { f2bf(acc[m][nf][0]), f2bf(acc[m][nf][1]),
                          f2bf(acc[m][nf][2]), f2bf(acc[m][nf][3]) };
            *(short4v*)&xwT[(size_t)e * ROWS_ + nr] = o;
        }
}

// y2[b] = adj[b] @ xw[b] + bias, fused masked per-channel stats.
// xw^T slice held in registers per K-half; adj panel staged once in LDS.
__global__ __launch_bounds__(512, 3) void gemm_y2(const float* __restrict__ adj,
                                                  const short* __restrict__ xwT,
                                                  const float* __restrict__ bias,
                                                  const float* __restrict__ mask,
                                                  float* __restrict__ y2,
                                                  float* __restrict__ psum,
                                                  float* __restrict__ psumsq,
                                                  float* __restrict__ pcnt) {
    __shared__ short As[64 * 512];   // 64 KB, [row][k] swizzled
    const int tid = threadIdx.x, wv = tid >> 6, lane = tid & 63;
    const int lrow = lane & 15, lg = lane >> 4;
    // XCD-chunked swizzle: 64 consecutive work-items per XCD => a batch's
    // 8 row-tiles share one XCD's L2 (xwT slice resident)
    const int bid = blockIdx.x;
    const int swz = ((bid & 7) << 6) | (bid >> 3);
    const int bz = swz >> 3, mt = swz & 7;
    const int rowBase = mt * 64;
    const float* A = adj + (size_t)bz * N_ * N_;

    // B half 0: issued first, in flight during As staging
    bf16x8 b[2][8];
    #pragma unroll
    for (int nf = 0; nf < 2; ++nf) {
        const short* bp = &xwT[(size_t)(wv * 32 + nf * 16 + lrow) * ROWS_ +
                               bz * N_ + lg * 8];
        #pragma unroll
        for (int kk = 0; kk < 8; ++kk)
            b[nf][kk] = *(const bf16x8*)(bp + kk * 32);
    }
    // stage As once: 64 rows x 512 k, f32 -> bf16
    const int sr = tid >> 3, sk = (tid & 7) * 64;
    {
        const float* src = &A[(size_t)(rowBase + sr) * N_ + sk];
        short* dst = &As[sr * 512];
        #pragma unroll
        for (int j = 0; j < 8; ++j) {
            float4 v0 = *(const float4*)(src + j * 8);
            float4 v1 = *(const float4*)(src + j * 8 + 4);
            bf16x8 h = { f2bf(v0.x), f2bf(v0.y), f2bf(v0.z), f2bf(v0.w),
                         f2bf(v1.x), f2bf(v1.y), f2bf(v1.z), f2bf(v1.w) };
            int slot = (sk >> 3) + j;
            *(bf16x8*)(dst + (((slot ^ (sr & 7)) << 3))) = h;
        }
    }
    __syncthreads();

    f32x4 acc[4][2] = {};
    const int rb7 = lrow & 7;
    // K half 0
    #pragma unroll
    for (int kk = 0; kk < 8; ++kk) {
        bf16x8 a[4];
        #pragma unroll
        for (int m = 0; m < 4; ++m)
            a[m] = *(const bf16x8*)&As[(m * 16 + lrow) * 512 +
                                       (((kk * 4 + lg) ^ rb7) << 3)];
        #pragma unroll
        for (int m = 0; m < 4; ++m)
            #pragma unroll
            for (int nf = 0; nf < 2; ++nf)
                acc[m][nf] = __builtin_amdgcn_mfma_f32_16x16x32_bf16(
                    a[m], b[nf][kk], acc[m][nf], 0, 0, 0);
    }
    // reload B for K half 1 (in-place; lifetimes disjoint)
    #pragma unroll
    for (int nf = 0; nf < 2; ++nf) {
        const short* bp = &xwT[(size_t)(wv * 32 + nf * 16 + lrow) * ROWS_ +
                               bz * N_ + 256 + lg * 8];
        #pragma unroll
        for (int kk = 0; kk < 8; ++kk)
            b[nf][kk] = *(const bf16x8*)(bp + kk * 32);
    }
    // K half 1
    #pragma unroll
    for (int kk = 0; kk < 8; ++kk) {
        bf16x8 a[4];
        #pragma unroll
        for (int m = 0; m < 4; ++m)
            a[m] = *(const bf16x8*)&As[(m * 16 + lrow) * 512 +
                                       (((32 + kk * 4 + lg) ^ rb7) << 3)];
        #pragma unroll
        for (int m = 0; m < 4; ++m)
            #pragma unroll
            for (int nf = 0; nf < 2; ++nf)
                acc[m][nf] = __builtin_amdgcn_mfma_f32_16x16x32_bf16(
                    a[m], b[nf][kk], acc[m][nf], 0, 0, 0);
    }

    // epilogue: bias + store + masked per-channel stats (wave owns 32 cols)
    float* C = y2 + (size_t)bz * N_ * DOUT_;
    float mv[4][4];
    #pragma unroll
    for (int m = 0; m < 4; ++m)
        #pragma unroll
        for (int r = 0; r < 4; ++r)
            mv[m][r] = mask[bz * N_ + rowBase + m * 16 + lg * 4 + r];
    float sv[2] = {0.f, 0.f}, sq[2] = {0.f, 0.f};
    #pragma unroll
    for (int nf = 0; nf < 2; ++nf) {
        const int col = wv * 32 + nf * 16 + lrow;
        const float bv = bias[col];
        #pragma unroll
        for (int m = 0; m < 4; ++m) {
            const int r0 = rowBase + m * 16 + lg * 4;
            #pragma unroll
            for (int r = 0; r < 4; ++r) {
                float v = acc[m][nf][r] + bv;
                C[(size_t)(r0 + r) * DOUT_ + col] = v;
                float vm = v * mv[m][r];
                sv[nf] += vm;
                sq[nf] = fmaf(v, vm, sq[nf]);
            }
        }
    }
    #pragma unroll
    for (int nf = 0; nf < 2; ++nf) {
        sv[nf] += __shfl_xor(sv[nf], 16); sv[nf] += __shfl_xor(sv[nf], 32);
        sq[nf] += __shfl_xor(sq[nf], 16); sq[nf] += __shfl_xor(sq[nf], 32);
    }
    const int pidx = bz * 8 + mt;
    if (lg == 0) {
        #pragma unroll
        for (int nf = 0; nf < 2; ++nf) {
            psum[(size_t)pidx * DOUT_ + wv * 32 + nf * 16 + lrow]   = sv[nf];
            psumsq[(size_t)pidx * DOUT_ + wv * 32 + nf * 16 + lrow] = sq[nf];
        }
    }
    if (wv == 0) {
        float cnt = mask[bz * N_ + rowBase + lane];
        #pragma unroll
        for (int i = 1; i < 64; i <<= 1) cnt += __shfl_xor(cnt, i);
        if (lane == 0) pcnt[pidx] = cnt;
    }
}

// column-parallel finalize: one block per channel e
__global__ __launch_bounds__(256) void finalize2(const float* __restrict__ psum,
                                                 const float* __restrict__ psumsq,
                                                 const float* __restrict__ pcnt,
                                                 const float* __restrict__ gamma,
                                                 const float* __restrict__ beta,
                                                 float* __restrict__ scsh) {
    const int e = blockIdx.x, t = threadIdx.x;
    float s  = psum[(size_t)t * DOUT_ + e]   + psum[(size_t)(t + 256) * DOUT_ + e];
    float ss = psumsq[(size_t)t * DOUT_ + e] + psumsq[(size_t)(t + 256) * DOUT_ + e];
    float n  = pcnt[t] + pcnt[t + 256];
    #pragma unroll
    for (int i = 1; i < 64; i <<= 1) {
        s += __shfl_xor(s, i); ss += __shfl_xor(ss, i); n += __shfl_xor(n, i);
    }
    __shared__ float red[3][4];
    const int wv = t >> 6;
    if ((t & 63) == 0) { red[0][wv] = s; red[1][wv] = ss; red[2][wv] = n; }
    __syncthreads();
    if (t == 0) {
        s  = red[0][0] + red[0][1] + red[0][2] + red[0][3];
        ss = red[1][0] + red[1][1] + red[1][2] + red[1][3];
        n  = red[2][0] + red[2][1] + red[2][2] + red[2][3];
        float mean = s / n;
        float var = ss / n - mean * mean;
        float sc = rsqrtf(var + EPS_) * gamma[e];
        scsh[e] = sc;
        scsh[DOUT_ + e] = beta[e] - mean * sc;
    }
}

__global__ __launch_bounds__(256) void norm_relu(float* __restrict__ y2,
                                                 const float* __restrict__ mask,
                                                 const float* __restrict__ scsh) {
    const int nq = ROWS_ * (DOUT_ / 4);
    for (int q = blockIdx.x * blockDim.x + threadIdx.x; q < nq;
         q += gridDim.x * blockDim.x) {
        int e4 = (q & 63) * 4;
        int r = q >> 6;
        float m = mask[r];
        float4 v  = *(float4*)&y2[(size_t)q * 4];
        float4 sc = *(const float4*)&scsh[e4];
        float4 sh = *(const float4*)&scsh[DOUT_ + e4];
        v.x = fmaxf(fmaf(v.x, sc.x, sh.x) * m, 0.f);
        v.y = fmaxf(fmaf(v.y, sc.y, sh.y) * m, 0.f);
        v.z = fmaxf(fmaf(v.z, sc.z, sh.z) * m, 0.f);
        v.w = fmaxf(fmaf(v.w, sc.w, sh.w) * m, 0.f);
        *(float4*)&y2[(size_t)q * 4] = v;
    }
}

extern "C" void kernel_launch(void* const* d_in, const int* in_sizes, int n_in,
                              void* d_out, int out_size, void* d_ws, size_t ws_size,
                              hipStream_t stream) {
    const float* x      = (const float*)d_in[0];
    const float* adj    = (const float*)d_in[1];
    const float* mask   = (const float*)d_in[2];
    const float* weight = (const float*)d_in[3];
    const float* bias   = (const float*)d_in[4];
    const float* gamma  = (const float*)d_in[5];
    const float* beta   = (const float*)d_in[6];
    float* out = (float*)d_out;

    short* WT     = (short*)d_ws;                          // 128 KB
    short* xwT    = WT + 256 * 256;                        // 16.8 MB
    float* psum   = (float*)(xwT + (size_t)DOUT_ * ROWS_); // 512 KB
    float* psumsq = psum + NBLK_Y2 * DOUT_;                // 512 KB
    float* pcnt   = psumsq + NBLK_Y2 * DOUT_;              // 2 KB
    float* scsh   = pcnt + NBLK_Y2;                        // 2 KB

    wt_cvt<<<16, 256, 0, stream>>>(weight, WT);
    gemm_xw<<<512, 512, 0, stream>>>(x, WT, xwT);
    gemm_y2<<<512, 512, 0, stream>>>(adj, xwT, bias, mask, out, psum, psumsq, pcnt);
    finalize2<<<256, 256, 0, stream>>>(psum, psumsq, pcnt, gamma, beta, scsh);
    norm_relu<<<2048, 256, 0, stream>>>(out, mask, scsh);
}

// Round 5
// 55.991 us; speedup vs baseline: 4.0460x; 1.3022x over previous
//
#include <hip/hip_runtime.h>

#define B_    64
#define N_    512
#define DIN_  256
#define DOUT_ 256
#define EPS_  1e-5f
#define ROWS_ (B_ * N_)   // 32768
#define NBLK_Y2 512

typedef __attribute__((ext_vector_type(8))) short bf16x8;   // 8 bf16 = 4 VGPRs
typedef __attribute__((ext_vector_type(4))) float f32x4;
typedef __attribute__((ext_vector_type(4))) short short4v;

__device__ __forceinline__ short f2bf(float f) {
    unsigned u = __builtin_bit_cast(unsigned, f);
    u += 0x7fff + ((u >> 16) & 1);     // round-to-nearest-even
    return (short)(u >> 16);
}

// async global->LDS, 16B/lane; both sides linear in tid => plain DMA
__device__ __forceinline__ void gload_lds16(const void* g, void* l) {
    __builtin_amdgcn_global_load_lds(
        (const __attribute__((address_space(1))) void*)g,
        (__attribute__((address_space(3))) void*)l, 16, 0, 0);
}

// Fragment order everywhere: [kfrag][efrag(16 cols)][lane(64)][8 shorts].
// Lane l of frag (kf,ef) holds col = ef*16 + (l&15), k = kf*32 + (l>>4)*8 .. +8.

// WTf: W[k][e] -> fragment order. 8 kf x 16 ef x 64 lanes = 8192 chunks of 16B.
__global__ __launch_bounds__(256) void wt_cvt(const float* __restrict__ W,
                                              short* __restrict__ WTf) {
    const int c = blockIdx.x * 256 + threadIdx.x;   // 0..8191
    const int kf = c >> 10, ef = (c >> 6) & 15, lp = c & 63;
    const int e = ef * 16 + (lp & 15);
    const int k0 = kf * 32 + (lp >> 4) * 8;
    bf16x8 h;
    #pragma unroll
    for (int j = 0; j < 8; ++j)
        h[j] = f2bf(W[(size_t)(k0 + j) * DOUT_ + e]);
    *(bf16x8*)&WTf[(size_t)c * 8] = h;
}

// xw = x @ W, output in per-batch fragment order xwT[b][kf16][ef16][64][8].
// 2-phase pipeline, BK=64 (2 kfrags/chunk), 4 chunks.
__global__ __launch_bounds__(512, 4) void gemm_xw(const float* __restrict__ X,
                                                  const short* __restrict__ WTf,
                                                  short* __restrict__ xwT) {
    __shared__ __align__(16) short Bs[2][16384];   // 32 KB/buf
    __shared__ __align__(16) short As[2][4096];    //  8 KB/buf
    const int tid = threadIdx.x, wv = tid >> 6, lane = tid & 63;
    const int lrow = lane & 15, lg = lane >> 4;
    const int bid = blockIdx.x;
    const int rowBase = bid * 64;

    // A staging: thread owns one 16B slot: (kf2, rf, lane')
    const int s_row = ((tid >> 6) & 3) * 16 + (tid & 15);
    const int s_kloc = (tid >> 8) * 32 + ((tid >> 4) & 3) * 8;
    const float* Xr = &X[(size_t)(rowBase + s_row) * DIN_ + s_kloc];

    f32x4 acc[4][2] = {};
    float4 av0, av1;

    // ---- prologue: chunk 0 ----
    av0 = *(const float4*)(Xr);
    av1 = *(const float4*)(Xr + 4);
    #pragma unroll
    for (int j = 0; j < 4; ++j) {
        int o = tid * 16 + j * 8192;
        gload_lds16((const char*)WTf + o, (char*)&Bs[0][0] + o);
    }
    {
        bf16x8 h = { f2bf(av0.x), f2bf(av0.y), f2bf(av0.z), f2bf(av0.w),
                     f2bf(av1.x), f2bf(av1.y), f2bf(av1.z), f2bf(av1.w) };
        *(bf16x8*)((char*)&As[0][0] + tid * 16) = h;
    }
    __syncthreads();

    int cur = 0;
    for (int c = 0; c < 4; ++c) {
        if (c < 3) {   // issue A-loads first, then B-DMA (A wait leaves B in flight)
            av0 = *(const float4*)(Xr + (c + 1) * 64);
            av1 = *(const float4*)(Xr + (c + 1) * 64 + 4);
            #pragma unroll
            for (int j = 0; j < 4; ++j) {
                int o = tid * 16 + j * 8192;
                gload_lds16((const char*)WTf + (c + 1) * 32768 + o,
                            (char*)&Bs[cur ^ 1][0] + o);
            }
        }
        #pragma unroll
        for (int kf2 = 0; kf2 < 2; ++kf2) {
            bf16x8 a[4], b[2];
            #pragma unroll
            for (int m = 0; m < 4; ++m)
                a[m] = *(const bf16x8*)((char*)&As[cur][0] +
                                        ((kf2 * 4 + m) * 64 + lane) * 16);
            #pragma unroll
            for (int nf = 0; nf < 2; ++nf)
                b[nf] = *(const bf16x8*)((char*)&Bs[cur][0] +
                                         ((kf2 * 16 + wv * 2 + nf) * 64 + lane) * 16);
            #pragma unroll
            for (int m = 0; m < 4; ++m)
                #pragma unroll
                for (int nf = 0; nf < 2; ++nf)
                    acc[m][nf] = __builtin_amdgcn_mfma_f32_16x16x32_bf16(
                        a[m], b[nf], acc[m][nf], 0, 0, 0);
        }
        if (c < 3) {
            bf16x8 h = { f2bf(av0.x), f2bf(av0.y), f2bf(av0.z), f2bf(av0.w),
                         f2bf(av1.x), f2bf(av1.y), f2bf(av1.z), f2bf(av1.w) };
            *(bf16x8*)((char*)&As[cur ^ 1][0] + tid * 16) = h;
        }
        __syncthreads();
        cur ^= 1;
    }

    // epilogue: write fragment-order bf16 into this batch's slice
    const int bz = bid >> 3, kfbase = (bid & 7) * 2;
    short* xwb = xwT + (size_t)bz * 131072;
    #pragma unroll
    for (int m = 0; m < 4; ++m)
        #pragma unroll
        for (int nf = 0; nf < 2; ++nf) {
            int kf = kfbase + (m >> 1);
            int ef = wv * 2 + nf;
            int lanep = lrow + 16 * ((m & 1) * 2 + (lg >> 1));
            size_t off = ((size_t)(kf * 16 + ef) * 64 + lanep) * 8 + (lg & 1) * 4;
            short4v o = { f2bf(acc[m][nf][0]), f2bf(acc[m][nf][1]),
                          f2bf(acc[m][nf][2]), f2bf(acc[m][nf][3]) };
            *(short4v*)&xwb[off] = o;
        }
}

// y2[b] = adj[b] @ xw[b] + bias, fused masked per-channel stats.
// B = xw slice in fragment order (linear DMA); 8 chunks of BK=64.
__global__ __launch_bounds__(512, 4) void gemm_y2(const float* __restrict__ adj,
                                                  const short* __restrict__ xwT,
                                                  const float* __restrict__ bias,
                                                  const float* __restrict__ mask,
                                                  float* __restrict__ y2,
                                                  float* __restrict__ psum,
                                                  float* __restrict__ psumsq,
                                                  float* __restrict__ pcnt) {
    __shared__ __align__(16) short Bs[2][16384];   // 32 KB/buf
    __shared__ __align__(16) short As[2][4096];    //  8 KB/buf
    const int tid = threadIdx.x, wv = tid >> 6, lane = tid & 63;
    const int lrow = lane & 15, lg = lane >> 4;
    // XCD-chunked swizzle: 64 consecutive work-items per XCD
    const int bid = blockIdx.x;
    const int swz = ((bid & 7) << 6) | (bid >> 3);
    const int bz = swz >> 3, mt = swz & 7;
    const int rowBase = mt * 64;
    const float* A = adj + (size_t)bz * N_ * N_;
    const short* xwb = xwT + (size_t)bz * 131072;

    const int s_row = ((tid >> 6) & 3) * 16 + (tid & 15);
    const int s_kloc = (tid >> 8) * 32 + ((tid >> 4) & 3) * 8;
    const float* Ar = &A[(size_t)(rowBase + s_row) * N_ + s_kloc];

    f32x4 acc[4][2] = {};
    float4 av0, av1;

    // ---- prologue: chunk 0 ----
    av0 = *(const float4*)(Ar);
    av1 = *(const float4*)(Ar + 4);
    #pragma unroll
    for (int j = 0; j < 4; ++j) {
        int o = tid * 16 + j * 8192;
        gload_lds16((const char*)xwb + o, (char*)&Bs[0][0] + o);
    }
    {
        bf16x8 h = { f2bf(av0.x), f2bf(av0.y), f2bf(av0.z), f2bf(av0.w),
                     f2bf(av1.x), f2bf(av1.y), f2bf(av1.z), f2bf(av1.w) };
        *(bf16x8*)((char*)&As[0][0] + tid * 16) = h;
    }
    __syncthreads();

    int cur = 0;
    for (int c = 0; c < 8; ++c) {
        if (c < 7) {
            av0 = *(const float4*)(Ar + (c + 1) * 64);
            av1 = *(const float4*)(Ar + (c + 1) * 64 + 4);
            #pragma unroll
            for (int j = 0; j < 4; ++j) {
                int o = tid * 16 + j * 8192;
                gload_lds16((const char*)xwb + (c + 1) * 32768 + o,
                            (char*)&Bs[cur ^ 1][0] + o);
            }
        }
        #pragma unroll
        for (int kf2 = 0; kf2 < 2; ++kf2) {
            bf16x8 a[4], b[2];
            #pragma unroll
            for (int m = 0; m < 4; ++m)
                a[m] = *(const bf16x8*)((char*)&As[cur][0] +
                                        ((kf2 * 4 + m) * 64 + lane) * 16);
            #pragma unroll
            for (int nf = 0; nf < 2; ++nf)
                b[nf] = *(const bf16x8*)((char*)&Bs[cur][0] +
                                         ((kf2 * 16 + wv * 2 + nf) * 64 + lane) * 16);
            #pragma unroll
            for (int m = 0; m < 4; ++m)
                #pragma unroll
                for (int nf = 0; nf < 2; ++nf)
                    acc[m][nf] = __builtin_amdgcn_mfma_f32_16x16x32_bf16(
                        a[m], b[nf], acc[m][nf], 0, 0, 0);
        }
        if (c < 7) {
            bf16x8 h = { f2bf(av0.x), f2bf(av0.y), f2bf(av0.z), f2bf(av0.w),
                         f2bf(av1.x), f2bf(av1.y), f2bf(av1.z), f2bf(av1.w) };
            *(bf16x8*)((char*)&As[cur ^ 1][0] + tid * 16) = h;
        }
        __syncthreads();
        cur ^= 1;
    }

    // ---- epilogue: bias + store + masked per-channel stats ----
    float* C = y2 + (size_t)bz * N_ * DOUT_;
    float mv[4][4];
    #pragma unroll
    for (int m = 0; m < 4; ++m)
        #pragma unroll
        for (int r = 0; r < 4; ++r)
            mv[m][r] = mask[bz * N_ + rowBase + m * 16 + lg * 4 + r];
    float sv[2] = {0.f, 0.f}, sq[2] = {0.f, 0.f};
    #pragma unroll
    for (int nf = 0; nf < 2; ++nf) {
        const int col = wv * 32 + nf * 16 + lrow;
        const float bv = bias[col];
        #pragma unroll
        for (int m = 0; m < 4; ++m) {
            const int r0 = rowBase + m * 16 + lg * 4;
            #pragma unroll
            for (int r = 0; r < 4; ++r) {
                float v = acc[m][nf][r] + bv;
                C[(size_t)(r0 + r) * DOUT_ + col] = v;
                float vm = v * mv[m][r];
                sv[nf] += vm;
                sq[nf] = fmaf(v, vm, sq[nf]);
            }
        }
    }
    #pragma unroll
    for (int nf = 0; nf < 2; ++nf) {
        sv[nf] += __shfl_xor(sv[nf], 16); sv[nf] += __shfl_xor(sv[nf], 32);
        sq[nf] += __shfl_xor(sq[nf], 16); sq[nf] += __shfl_xor(sq[nf], 32);
    }
    const int pidx = bz * 8 + mt;
    if (lg == 0) {
        #pragma unroll
        for (int nf = 0; nf < 2; ++nf) {
            psum[(size_t)pidx * DOUT_ + wv * 32 + nf * 16 + lrow]   = sv[nf];
            psumsq[(size_t)pidx * DOUT_ + wv * 32 + nf * 16 + lrow] = sq[nf];
        }
    }
    if (wv == 0) {
        float cnt = mask[bz * N_ + rowBase + lane];
        #pragma unroll
        for (int i = 1; i < 64; i <<= 1) cnt += __shfl_xor(cnt, i);
        if (lane == 0) pcnt[pidx] = cnt;
    }
}

// column-parallel finalize: one block per channel e
__global__ __launch_bounds__(256) void finalize2(const float* __restrict__ psum,
                                                 const float* __restrict__ psumsq,
                                                 const float* __restrict__ pcnt,
                                                 const float* __restrict__ gamma,
                                                 const float* __restrict__ beta,
                                                 float* __restrict__ scsh) {
    const int e = blockIdx.x, t = threadIdx.x;
    float s  = psum[(size_t)t * DOUT_ + e]   + psum[(size_t)(t + 256) * DOUT_ + e];
    float ss = psumsq[(size_t)t * DOUT_ + e] + psumsq[(size_t)(t + 256) * DOUT_ + e];
    float n  = pcnt[t] + pcnt[t + 256];
    #pragma unroll
    for (int i = 1; i < 64; i <<= 1) {
        s += __shfl_xor(s, i); ss += __shfl_xor(ss, i); n += __shfl_xor(n, i);
    }
    __shared__ float red[3][4];
    const int wv = t >> 6;
    if ((t & 63) == 0) { red[0][wv] = s; red[1][wv] = ss; red[2][wv] = n; }
    __syncthreads();
    if (t == 0) {
        s  = red[0][0] + red[0][1] + red[0][2] + red[0][3];
        ss = red[1][0] + red[1][1] + red[1][2] + red[1][3];
        n  = red[2][0] + red[2][1] + red[2][2] + red[2][3];
        float mean = s / n;
        float var = ss / n - mean * mean;
        float sc = rsqrtf(var + EPS_) * gamma[e];
        scsh[e] = sc;
        scsh[DOUT_ + e] = beta[e] - mean * sc;
    }
}

__global__ __launch_bounds__(256) void norm_relu(float* __restrict__ y2,
                                                 const float* __restrict__ mask,
                                                 const float* __restrict__ scsh) {
    const int nq = ROWS_ * (DOUT_ / 4);
    for (int q = blockIdx.x * blockDim.x + threadIdx.x; q < nq;
         q += gridDim.x * blockDim.x) {
        int e4 = (q & 63) * 4;
        int r = q >> 6;
        float m = mask[r];
        float4 v  = *(float4*)&y2[(size_t)q * 4];
        float4 sc = *(const float4*)&scsh[e4];
        float4 sh = *(const float4*)&scsh[DOUT_ + e4];
        v.x = fmaxf(fmaf(v.x, sc.x, sh.x) * m, 0.f);
        v.y = fmaxf(fmaf(v.y, sc.y, sh.y) * m, 0.f);
        v.z = fmaxf(fmaf(v.z, sc.z, sh.z) * m, 0.f);
        v.w = fmaxf(fmaf(v.w, sc.w, sh.w) * m, 0.f);
        *(float4*)&y2[(size_t)q * 4] = v;
    }
}

extern "C" void kernel_launch(void* const* d_in, const int* in_sizes, int n_in,
                              void* d_out, int out_size, void* d_ws, size_t ws_size,
                              hipStream_t stream) {
    const float* x      = (const float*)d_in[0];
    const float* adj    = (const float*)d_in[1];
    const float* mask   = (const float*)d_in[2];
    const float* weight = (const float*)d_in[3];
    const float* bias   = (const float*)d_in[4];
    const float* gamma  = (const float*)d_in[5];
    const float* beta   = (const float*)d_in[6];
    float* out = (float*)d_out;

    short* WTf    = (short*)d_ws;                          // 128 KB (frag order)
    short* xwT    = WTf + 256 * 256;                       // 16.8 MB (frag order)
    float* psum   = (float*)(xwT + (size_t)DOUT_ * ROWS_); // 512 KB
    float* psumsq = psum + NBLK_Y2 * DOUT_;                // 512 KB
    float* pcnt   = psumsq + NBLK_Y2 * DOUT_;              // 2 KB
    float* scsh   = pcnt + NBLK_Y2;                        // 2 KB

    wt_cvt<<<32, 256, 0, stream>>>(weight, WTf);
    gemm_xw<<<512, 512, 0, stream>>>(x, WTf, xwT);
    gemm_y2<<<512, 512, 0, stream>>>(adj, xwT, bias, mask, out, psum, psumsq, pcnt);
    finalize2<<<256, 256, 0, stream>>>(psum, psumsq, pcnt, gamma, beta, scsh);
    norm_relu<<<2048, 256, 0, stream>>>(out, mask, scsh);
}

// Round 6
// 55.195 us; speedup vs baseline: 4.1043x; 1.0144x over previous
//
#include <hip/hip_runtime.h>

#define B_    64
#define N_    512
#define DIN_  256
#define DOUT_ 256
#define EPS_  1e-5f
#define ROWS_ (B_ * N_)   // 32768
#define NBLK_Y2 512

typedef __attribute__((ext_vector_type(8))) short bf16x8;   // 8 bf16 = 4 VGPRs
typedef __attribute__((ext_vector_type(8))) unsigned short u16x8;
typedef __attribute__((ext_vector_type(4))) float f32x4;
typedef __attribute__((ext_vector_type(4))) short short4v;

__device__ __forceinline__ short f2bf(float f) {
    unsigned u = __builtin_bit_cast(unsigned, f);
    u += 0x7fff + ((u >> 16) & 1);     // round-to-nearest-even
    return (short)(u >> 16);
}

// async global->LDS, 16B/lane; both sides linear in tid => plain DMA
__device__ __forceinline__ void gload_lds16(const void* g, void* l) {
    __builtin_amdgcn_global_load_lds(
        (const __attribute__((address_space(1))) void*)g,
        (__attribute__((address_space(3))) void*)l, 16, 0, 0);
}

// Fragment order everywhere: [kfrag][efrag(16 cols)][lane(64)][8 shorts].
// Lane l of frag (kf,ef) holds col = ef*16 + (l&15), k = kf*32 + (l>>4)*8 .. +8.

// WTf: W[k][e] -> fragment order.
__global__ __launch_bounds__(256) void wt_cvt(const float* __restrict__ W,
                                              short* __restrict__ WTf) {
    const int c = blockIdx.x * 256 + threadIdx.x;   // 0..8191
    const int kf = c >> 10, ef = (c >> 6) & 15, lp = c & 63;
    const int e = ef * 16 + (lp & 15);
    const int k0 = kf * 32 + (lp >> 4) * 8;
    bf16x8 h;
    #pragma unroll
    for (int j = 0; j < 8; ++j)
        h[j] = f2bf(W[(size_t)(k0 + j) * DOUT_ + e]);
    *(bf16x8*)&WTf[(size_t)c * 8] = h;
}

// xw = x @ W, output in per-batch fragment order xwT[b][kf16][ef16][64][8].
// (unchanged from R5 — WTf is L2-resident, this kernel is not the bottleneck)
__global__ __launch_bounds__(512, 4) void gemm_xw(const float* __restrict__ X,
                                                  const short* __restrict__ WTf,
                                                  short* __restrict__ xwT) {
    __shared__ __align__(16) short Bs[2][16384];
    __shared__ __align__(16) short As[2][4096];
    const int tid = threadIdx.x, wv = tid >> 6, lane = tid & 63;
    const int lrow = lane & 15, lg = lane >> 4;
    const int bid = blockIdx.x;
    const int rowBase = bid * 64;

    const int s_row = ((tid >> 6) & 3) * 16 + (tid & 15);
    const int s_kloc = (tid >> 8) * 32 + ((tid >> 4) & 3) * 8;
    const float* Xr = &X[(size_t)(rowBase + s_row) * DIN_ + s_kloc];

    f32x4 acc[4][2] = {};
    float4 av0, av1;

    av0 = *(const float4*)(Xr);
    av1 = *(const float4*)(Xr + 4);
    #pragma unroll
    for (int j = 0; j < 4; ++j) {
        int o = tid * 16 + j * 8192;
        gload_lds16((const char*)WTf + o, (char*)&Bs[0][0] + o);
    }
    {
        bf16x8 h = { f2bf(av0.x), f2bf(av0.y), f2bf(av0.z), f2bf(av0.w),
                     f2bf(av1.x), f2bf(av1.y), f2bf(av1.z), f2bf(av1.w) };
        *(bf16x8*)((char*)&As[0][0] + tid * 16) = h;
    }
    __syncthreads();

    int cur = 0;
    for (int c = 0; c < 4; ++c) {
        if (c < 3) {
            av0 = *(const float4*)(Xr + (c + 1) * 64);
            av1 = *(const float4*)(Xr + (c + 1) * 64 + 4);
            #pragma unroll
            for (int j = 0; j < 4; ++j) {
                int o = tid * 16 + j * 8192;
                gload_lds16((const char*)WTf + (c + 1) * 32768 + o,
                            (char*)&Bs[cur ^ 1][0] + o);
            }
        }
        #pragma unroll
        for (int kf2 = 0; kf2 < 2; ++kf2) {
            bf16x8 a[4], b[2];
            #pragma unroll
            for (int m = 0; m < 4; ++m)
                a[m] = *(const bf16x8*)((char*)&As[cur][0] +
                                        ((kf2 * 4 + m) * 64 + lane) * 16);
            #pragma unroll
            for (int nf = 0; nf < 2; ++nf)
                b[nf] = *(const bf16x8*)((char*)&Bs[cur][0] +
                                         ((kf2 * 16 + wv * 2 + nf) * 64 + lane) * 16);
            #pragma unroll
            for (int m = 0; m < 4; ++m)
                #pragma unroll
                for (int nf = 0; nf < 2; ++nf)
                    acc[m][nf] = __builtin_amdgcn_mfma_f32_16x16x32_bf16(
                        a[m], b[nf], acc[m][nf], 0, 0, 0);
        }
        if (c < 3) {
            bf16x8 h = { f2bf(av0.x), f2bf(av0.y), f2bf(av0.z), f2bf(av0.w),
                         f2bf(av1.x), f2bf(av1.y), f2bf(av1.z), f2bf(av1.w) };
            *(bf16x8*)((char*)&As[cur ^ 1][0] + tid * 16) = h;
        }
        __syncthreads();
        cur ^= 1;
    }

    const int bz = bid >> 3, kfbase = (bid & 7) * 2;
    short* xwb = xwT + (size_t)bz * 131072;
    #pragma unroll
    for (int m = 0; m < 4; ++m)
        #pragma unroll
        for (int nf = 0; nf < 2; ++nf) {
            int kf = kfbase + (m >> 1);
            int ef = wv * 2 + nf;
            int lanep = lrow + 16 * ((m & 1) * 2 + (lg >> 1));
            size_t off = ((size_t)(kf * 16 + ef) * 64 + lanep) * 8 + (lg & 1) * 4;
            short4v o = { f2bf(acc[m][nf][0]), f2bf(acc[m][nf][1]),
                          f2bf(acc[m][nf][2]), f2bf(acc[m][nf][3]) };
            *(short4v*)&xwb[off] = o;
        }
}

// y2[b] = adj[b] @ xw[b] + bias, fused masked stats.
// Counted-vmcnt pipeline: BK=32, B 4-deep (3 chunks in flight), A 2-deep.
// Raw s_barrier; never vmcnt(0) in the loop.
template <bool BF16Y2>
__global__ __launch_bounds__(512, 4) void gemm_y2(const float* __restrict__ adj,
                                                  const short* __restrict__ xwT,
                                                  const float* __restrict__ bias,
                                                  const float* __restrict__ mask,
                                                  float* __restrict__ outf,
                                                  unsigned short* __restrict__ y2b,
                                                  float* __restrict__ psum,
                                                  float* __restrict__ psumsq,
                                                  float* __restrict__ pcnt) {
    __shared__ __align__(16) short Bs[4][8192];   // 4 x 16 KB
    __shared__ __align__(16) short As[2][2048];   // 2 x  4 KB
    const int tid = threadIdx.x, wv = tid >> 6, lane = tid & 63;
    const int lrow = lane & 15, lg = lane >> 4;
    const int bid = blockIdx.x;
    const int swz = ((bid & 7) << 6) | (bid >> 3);   // XCD-chunked
    const int bz = swz >> 3, mt = swz & 7;
    const int rowBase = mt * 64;
    const float* A = adj + (size_t)bz * N_ * N_;
    const short* xwb = xwT + (size_t)bz * 131072;

    // A staging: thread t owns As bytes [8t, 8t+8) = frag slot t>>1, half t&1
    const int arow = ((tid >> 7) << 4) | ((tid >> 1) & 15);
    const int akl  = (((tid >> 5) & 3) << 3) | ((tid & 1) << 2);
    const float* Ar = &A[(size_t)(rowBase + arow) * N_ + akl];

    float4 av[2];
    f32x4 acc[4][2] = {};

    // ---- prologue: A(0),A(1) regs; B(0..2) DMA; write A(0) ----
    float4 av0t = *(const float4*)(Ar);
    av[1] = *(const float4*)(Ar + 32);
    __builtin_amdgcn_sched_barrier(0);
    #pragma unroll
    for (int p = 0; p < 3; ++p) {
        const char* src = (const char*)xwb + p * 16384;
        char* dst = (char*)&Bs[p][0];
        gload_lds16(src + tid * 16, dst + tid * 16);
        gload_lds16(src + tid * 16 + 8192, dst + tid * 16 + 8192);
    }
    __builtin_amdgcn_sched_barrier(0);
    {
        short4v h = { f2bf(av0t.x), f2bf(av0t.y), f2bf(av0t.z), f2bf(av0t.w) };
        *(short4v*)((char*)&As[0][0] + tid * 8) = h;
    }
    asm volatile("s_waitcnt lgkmcnt(0)" ::: "memory");
    asm volatile("s_waitcnt vmcnt(4)" ::: "memory");   // B(0) landed
    __builtin_amdgcn_s_barrier();
    asm volatile("" ::: "memory");

    #pragma unroll 1
    for (int cc = 0; cc < 16; cc += 4) {
        #pragma unroll
        for (int u = 0; u < 4; ++u) {
            const int c = cc + u;
            // 1) issue A(c+2) glb load (A before B => cvt-wait preserves B depth)
            {
                const int cn = (c + 2 < 16) ? c + 2 : 15;
                av[c & 1] = *(const float4*)(Ar + cn * 32);
            }
            __builtin_amdgcn_sched_barrier(0);
            // 2) issue B(c+3) DMA into buf (c+3)&3 (read last at compute c-1)
            {
                const int cn = (c + 3 < 16) ? c + 3 : 15;
                const char* src = (const char*)xwb + cn * 16384;
                char* dst = (char*)&Bs[(c + 3) & 3][0];
                gload_lds16(src + tid * 16, dst + tid * 16);
                gload_lds16(src + tid * 16 + 8192, dst + tid * 16 + 8192);
            }
            __builtin_amdgcn_sched_barrier(0);
            // 3) compute chunk c from As[c&1], Bs[c&3]
            {
                const char* ab = (const char*)&As[c & 1][0];
                const char* bb = (const char*)&Bs[c & 3][0];
                bf16x8 a0 = *(const bf16x8*)(ab + (0 * 64 + lane) * 16);
                bf16x8 a1 = *(const bf16x8*)(ab + (1 * 64 + lane) * 16);
                bf16x8 a2 = *(const bf16x8*)(ab + (2 * 64 + lane) * 16);
                bf16x8 a3 = *(const bf16x8*)(ab + (3 * 64 + lane) * 16);
                bf16x8 b0 = *(const bf16x8*)(bb + ((wv * 2 + 0) * 64 + lane) * 16);
                bf16x8 b1 = *(const bf16x8*)(bb + ((wv * 2 + 1) * 64 + lane) * 16);
                acc[0][0] = __builtin_amdgcn_mfma_f32_16x16x32_bf16(a0, b0, acc[0][0], 0, 0, 0);
                acc[0][1] = __builtin_amdgcn_mfma_f32_16x16x32_bf16(a0, b1, acc[0][1], 0, 0, 0);
                acc[1][0] = __builtin_amdgcn_mfma_f32_16x16x32_bf16(a1, b0, acc[1][0], 0, 0, 0);
                acc[1][1] = __builtin_amdgcn_mfma_f32_16x16x32_bf16(a1, b1, acc[1][1], 0, 0, 0);
                acc[2][0] = __builtin_amdgcn_mfma_f32_16x16x32_bf16(a2, b0, acc[2][0], 0, 0, 0);
                acc[2][1] = __builtin_amdgcn_mfma_f32_16x16x32_bf16(a2, b1, acc[2][1], 0, 0, 0);
                acc[3][0] = __builtin_amdgcn_mfma_f32_16x16x32_bf16(a3, b0, acc[3][0], 0, 0, 0);
                acc[3][1] = __builtin_amdgcn_mfma_f32_16x16x32_bf16(a3, b1, acc[3][1], 0, 0, 0);
            }
            __builtin_amdgcn_sched_barrier(0);
            // 4) cvt + ds_write A(c+1); compiler's wait for av retires B(c+1)
            {
                float4 v = av[(c + 1) & 1];
                short4v h = { f2bf(v.x), f2bf(v.y), f2bf(v.z), f2bf(v.w) };
                *(short4v*)((char*)&As[(c + 1) & 1][0] + tid * 8) = h;
            }
            asm volatile("s_waitcnt lgkmcnt(0)" ::: "memory");
            asm volatile("s_waitcnt vmcnt(5)" ::: "memory");  // keep 3 chunks in flight
            __builtin_amdgcn_s_barrier();
            asm volatile("" ::: "memory");
        }
    }

    // ---- epilogue: bias + store (bf16 or f32) + masked per-channel stats ----
    float* C = outf + (size_t)bz * N_ * DOUT_;
    unsigned short* Cb = y2b + (size_t)bz * N_ * DOUT_;
    float mv[4][4];
    #pragma unroll
    for (int m = 0; m < 4; ++m)
        #pragma unroll
        for (int r = 0; r < 4; ++r)
            mv[m][r] = mask[bz * N_ + rowBase + m * 16 + lg * 4 + r];
    float sv[2] = {0.f, 0.f}, sq[2] = {0.f, 0.f};
    #pragma unroll
    for (int nf = 0; nf < 2; ++nf) {
        const int col = wv * 32 + nf * 16 + lrow;
        const float bv = bias[col];
        #pragma unroll
        for (int m = 0; m < 4; ++m) {
            const int r0 = rowBase + m * 16 + lg * 4;
            #pragma unroll
            for (int r = 0; r < 4; ++r) {
                float v = acc[m][nf][r] + bv;
                if (BF16Y2)
                    Cb[(size_t)(r0 + r) * DOUT_ + col] = (unsigned short)f2bf(v);
                else
                    C[(size_t)(r0 + r) * DOUT_ + col] = v;
                float vm = v * mv[m][r];
                sv[nf] += vm;
                sq[nf] = fmaf(v, vm, sq[nf]);
            }
        }
    }
    #pragma unroll
    for (int nf = 0; nf < 2; ++nf) {
        sv[nf] += __shfl_xor(sv[nf], 16); sv[nf] += __shfl_xor(sv[nf], 32);
        sq[nf] += __shfl_xor(sq[nf], 16); sq[nf] += __shfl_xor(sq[nf], 32);
    }
    const int pidx = bz * 8 + mt;
    if (lg == 0) {
        #pragma unroll
        for (int nf = 0; nf < 2; ++nf) {
            psum[(size_t)pidx * DOUT_ + wv * 32 + nf * 16 + lrow]   = sv[nf];
            psumsq[(size_t)pidx * DOUT_ + wv * 32 + nf * 16 + lrow] = sq[nf];
        }
    }
    if (wv == 0) {
        float cnt = mask[bz * N_ + rowBase + lane];
        #pragma unroll
        for (int i = 1; i < 64; i <<= 1) cnt += __shfl_xor(cnt, i);
        if (lane == 0) pcnt[pidx] = cnt;
    }
}

__global__ __launch_bounds__(256) void finalize2(const float* __restrict__ psum,
                                                 const float* __restrict__ psumsq,
                                                 const float* __restrict__ pcnt,
                                                 const float* __restrict__ gamma,
                                                 const float* __restrict__ beta,
                                                 float* __restrict__ scsh) {
    const int e = blockIdx.x, t = threadIdx.x;
    float s  = psum[(size_t)t * DOUT_ + e]   + psum[(size_t)(t + 256) * DOUT_ + e];
    float ss = psumsq[(size_t)t * DOUT_ + e] + psumsq[(size_t)(t + 256) * DOUT_ + e];
    float n  = pcnt[t] + pcnt[t + 256];
    #pragma unroll
    for (int i = 1; i < 64; i <<= 1) {
        s += __shfl_xor(s, i); ss += __shfl_xor(ss, i); n += __shfl_xor(n, i);
    }
    __shared__ float red[3][4];
    const int wv = t >> 6;
    if ((t & 63) == 0) { red[0][wv] = s; red[1][wv] = ss; red[2][wv] = n; }
    __syncthreads();
    if (t == 0) {
        s  = red[0][0] + red[0][1] + red[0][2] + red[0][3];
        ss = red[1][0] + red[1][1] + red[1][2] + red[1][3];
        n  = red[2][0] + red[2][1] + red[2][2] + red[2][3];
        float mean = s / n;
        float var = ss / n - mean * mean;
        float sc = rsqrtf(var + EPS_) * gamma[e];
        scsh[e] = sc;
        scsh[DOUT_ + e] = beta[e] - mean * sc;
    }
}

// out = relu((bf16(y2)*scale + shift) * mask), bf16 in -> f32 out
__global__ __launch_bounds__(256) void norm_relu_bf(const unsigned short* __restrict__ y2b,
                                                    const float* __restrict__ mask,
                                                    const float* __restrict__ scsh,
                                                    float* __restrict__ out) {
    const int nq = ROWS_ * (DOUT_ / 8);
    for (int q = blockIdx.x * blockDim.x + threadIdx.x; q < nq;
         q += gridDim.x * blockDim.x) {
        int e8 = (q & 31) * 8;
        int r = q >> 5;
        float m = mask[r];
        u16x8 uv = *(const u16x8*)&y2b[(size_t)q * 8];
        float4 sc0 = *(const float4*)&scsh[e8];
        float4 sc1 = *(const float4*)&scsh[e8 + 4];
        float4 sh0 = *(const float4*)&scsh[DOUT_ + e8];
        float4 sh1 = *(const float4*)&scsh[DOUT_ + e8 + 4];
        float4 o0, o1;
        #pragma unroll
        for (int j = 0; j < 4; ++j) {
            float f = __builtin_bit_cast(float, (unsigned)uv[j] << 16);
            (&o0.x)[j] = fmaxf(fmaf(f, (&sc0.x)[j], (&sh0.x)[j]) * m, 0.f);
        }
        #pragma unroll
        for (int j = 0; j < 4; ++j) {
            float f = __builtin_bit_cast(float, (unsigned)uv[j + 4] << 16);
            (&o1.x)[j] = fmaxf(fmaf(f, (&sc1.x)[j], (&sh1.x)[j]) * m, 0.f);
        }
        *(float4*)&out[(size_t)q * 8] = o0;
        *(float4*)&out[(size_t)q * 8 + 4] = o1;
    }
}

// fallback: f32 y2 in place
__global__ __launch_bounds__(256) void norm_relu_f32(float* __restrict__ y2,
                                                     const float* __restrict__ mask,
                                                     const float* __restrict__ scsh) {
    const int nq = ROWS_ * (DOUT_ / 4);
    for (int q = blockIdx.x * blockDim.x + threadIdx.x; q < nq;
         q += gridDim.x * blockDim.x) {
        int e4 = (q & 63) * 4;
        int r = q >> 6;
        float m = mask[r];
        float4 v  = *(float4*)&y2[(size_t)q * 4];
        float4 sc = *(const float4*)&scsh[e4];
        float4 sh = *(const float4*)&scsh[DOUT_ + e4];
        v.x = fmaxf(fmaf(v.x, sc.x, sh.x) * m, 0.f);
        v.y = fmaxf(fmaf(v.y, sc.y, sh.y) * m, 0.f);
        v.z = fmaxf(fmaf(v.z, sc.z, sh.z) * m, 0.f);
        v.w = fmaxf(fmaf(v.w, sc.w, sh.w) * m, 0.f);
        *(float4*)&y2[(size_t)q * 4] = v;
    }
}

extern "C" void kernel_launch(void* const* d_in, const int* in_sizes, int n_in,
                              void* d_out, int out_size, void* d_ws, size_t ws_size,
                              hipStream_t stream) {
    const float* x      = (const float*)d_in[0];
    const float* adj    = (const float*)d_in[1];
    const float* mask   = (const float*)d_in[2];
    const float* weight = (const float*)d_in[3];
    const float* bias   = (const float*)d_in[4];
    const float* gamma  = (const float*)d_in[5];
    const float* beta   = (const float*)d_in[6];
    float* out = (float*)d_out;

    const size_t xw_elems = (size_t)DOUT_ * ROWS_;          // shorts
    const size_t need_bf = 131072 + xw_elems * 2 * 2 +       // WTf + xwT + y2b
                           (size_t)NBLK_Y2 * DOUT_ * 4 * 2 + NBLK_Y2 * 4 + 2048 + 64;
    const bool use_bf = ws_size >= need_bf;

    short* WTf    = (short*)d_ws;                            // 128 KB
    short* xwT    = WTf + 256 * 256;                         // 16.8 MB
    unsigned short* y2b = (unsigned short*)(xwT + xw_elems); // 16.8 MB (bf path)
    float* psum   = use_bf ? (float*)(y2b + xw_elems) : (float*)(y2b);
    float* psumsq = psum + NBLK_Y2 * DOUT_;
    float* pcnt   = psumsq + NBLK_Y2 * DOUT_;
    float* scsh   = pcnt + NBLK_Y2;

    wt_cvt<<<32, 256, 0, stream>>>(weight, WTf);
    gemm_xw<<<512, 512, 0, stream>>>(x, WTf, xwT);
    if (use_bf) {
        gemm_y2<true><<<NBLK_Y2, 512, 0, stream>>>(adj, xwT, bias, mask, out, y2b,
                                                   psum, psumsq, pcnt);
        finalize2<<<256, 256, 0, stream>>>(psum, psumsq, pcnt, gamma, beta, scsh);
        norm_relu_bf<<<2048, 256, 0, stream>>>(y2b, mask, scsh, out);
    } else {
        gemm_y2<false><<<NBLK_Y2, 512, 0, stream>>>(adj, xwT, bias, mask, out, y2b,
                                                    psum, psumsq, pcnt);
        finalize2<<<256, 256, 0, stream>>>(psum, psumsq, pcnt, gamma, beta, scsh);
        norm_relu_f32<<<2048, 256, 0, stream>>>(out, mask, scsh);
    }
}